// Round 5
// baseline (925.360 us; speedup 1.0000x reference)
//
#include <hip/hip_runtime.h>
#include <math.h>

#define NN 50000
#define EE 800000
#define D 128
#define EDIM 32
#define LL 3
#define NT 2
#define ET 3
#define NB 196       // ceil(NN/256)
#define NPAD 50112   // multiple of 64; >= align64(c0)+c1 for any split
#define NT32 1566    // NPAD/32
#define NT64 783     // NPAD/64

// ---------------- node-type permutation (deterministic, scan-based) ----------------
__global__ __launch_bounds__(256) void k_pcount(const int* __restrict__ nt, int* __restrict__ pc) {
    __shared__ int s[256];
    int d = blockIdx.x * 256 + threadIdx.x;
    int ind = 0;
    if (d < NN) ind = (nt[d] == 0) ? 1 : 0x10000;
    s[threadIdx.x] = ind;
    __syncthreads();
    for (int st = 128; st; st >>= 1) {
        if (threadIdx.x < st) s[threadIdx.x] += s[threadIdx.x + st];
        __syncthreads();
    }
    if (threadIdx.x == 0) pc[blockIdx.x] = s[0];
}

__global__ __launch_bounds__(256) void k_pscan(const int* __restrict__ pc, int* __restrict__ po,
                                               int* __restrict__ meta) {
    __shared__ int s[256];
    int t = threadIdx.x;
    int v = (t < NB) ? pc[t] : 0;
    s[t] = v;
    __syncthreads();
    for (int st = 1; st < 256; st <<= 1) {
        int add = (t >= st) ? s[t - st] : 0;
        __syncthreads();
        s[t] += add;
        __syncthreads();
    }
    if (t < NB) po[t] = s[t] - v;
    if (t == 0) meta[3] = ((s[255] & 0xffff) + 63) & ~63;   // aligned type-1 base
}

__global__ __launch_bounds__(256) void k_passign(const int* __restrict__ nt, const int* __restrict__ po,
                                                 const int* __restrict__ meta,
                                                 int* __restrict__ pos, int* __restrict__ inv) {
    __shared__ int s[256];
    int t = threadIdx.x;
    int d = blockIdx.x * 256 + t;
    int ty = (d < NN) ? nt[d] : -1;
    int ind = (ty == 0) ? 1 : ((ty == 1) ? 0x10000 : 0);
    s[t] = ind;
    __syncthreads();
    for (int st = 1; st < 256; st <<= 1) {
        int add = (t >= st) ? s[t - st] : 0;
        __syncthreads();
        s[t] += add;
        __syncthreads();
    }
    if (d >= NN) return;
    int excl = s[t] - ind;
    int pop = po[blockIdx.x];
    int p;
    if (ty == 0) p = (pop & 0xffff) + (excl & 0xffff);
    else         p = meta[3] + (pop >> 16) + (excl >> 16);
    pos[d] = p;
    inv[p] = d;
}

__global__ __launch_bounds__(256) void k_permx(const float* __restrict__ x, const int* __restrict__ pos,
                                               float* __restrict__ h0) {
    int flat = blockIdx.x * 256 + threadIdx.x;
    if (flat >= NN * 32) return;
    int d = flat >> 5, f4 = flat & 31;
    int p = pos[d];
    ((float4*)h0)[(size_t)p * 32 + f4] = ((const float4*)x)[(size_t)d * 32 + f4];
}

// ---------------- histogram of dst ----------------
__global__ __launch_bounds__(256) void k_hist(const int* __restrict__ dst, int* __restrict__ deg) {
    int e = blockIdx.x * 256 + threadIdx.x;
    if (e < EE) atomicAdd(&deg[dst[e]], 1);
}

// ---------------- 2-level exclusive scan of deg ----------------
__global__ __launch_bounds__(256) void k_scan_bsum(const int* __restrict__ deg, int* __restrict__ bsum) {
    __shared__ int s[256];
    int t = threadIdx.x;
    int d = blockIdx.x * 256 + t;
    s[t] = (d < NN) ? deg[d] : 0;
    __syncthreads();
    for (int st = 128; st > 0; st >>= 1) {
        if (t < st) s[t] += s[t + st];
        __syncthreads();
    }
    if (t == 0) bsum[blockIdx.x] = s[0];
}

__global__ __launch_bounds__(256) void k_scan_boff(const int* __restrict__ bsum, int* __restrict__ boff) {
    __shared__ int s[256];
    int t = threadIdx.x;
    s[t] = (t < NB) ? bsum[t] : 0;
    __syncthreads();
    for (int st = 1; st < 256; st <<= 1) {
        int add = (t >= st) ? s[t - st] : 0;
        __syncthreads();
        s[t] += add;
        __syncthreads();
    }
    if (t < NB) boff[t] = (t == 0) ? 0 : s[t - 1];
}

__global__ __launch_bounds__(256) void k_scan_offs(const int* __restrict__ deg, const int* __restrict__ boff,
                                                   int* __restrict__ offs, int* __restrict__ cur) {
    __shared__ int s[256];
    int t = threadIdx.x;
    int d = blockIdx.x * 256 + t;
    int v = (d < NN) ? deg[d] : 0;
    s[t] = v;
    __syncthreads();
    for (int st = 1; st < 256; st <<= 1) {
        int add = (t >= st) ? s[t - st] : 0;
        __syncthreads();
        s[t] += add;
        __syncthreads();
    }
    if (d < NN) {
        int excl = s[t] - v + boff[blockIdx.x];
        offs[d] = excl;
        cur[d]  = excl;
    }
}

// ------------- per-edge scalars, layer-split esort: esort[l*EE + p] = {sp, A, B, 0} -------------
__global__ __launch_bounds__(256) void k_edge(const float* __restrict__ edge_attr,
                                              const float* __restrict__ edge_W,
                                              const float* __restrict__ edge_b,
                                              const float* __restrict__ emb,
                                              const int* __restrict__ ei,
                                              const int* __restrict__ etype,
                                              const int* __restrict__ pos,
                                              int* __restrict__ cur,
                                              float4* __restrict__ esort) {
    __shared__ float eWl[LL * ET * 2 * EDIM];
    __shared__ float ebd[LL * ET * 2];
    int t0 = threadIdx.x;
    for (int i = t0; i < LL * ET * 2 * EDIM; i += 256) eWl[i] = edge_W[i];
    __syncthreads();
    if (t0 < LL * ET * 2) {
        int l = t0 / (ET * 2);
        int rem = t0 % (ET * 2);
        int tt = rem / 2;
        float sum = edge_b[t0];
        const float* em = emb + (l * ET + tt) * EDIM;
        const float* w  = eWl + t0 * EDIM;
        for (int c = 0; c < EDIM; c++) sum += em[c] * w[c];
        ebd[t0] = sum;
    }
    __syncthreads();
    int e = blockIdx.x * 256 + t0;
    if (e >= EE) return;

    float a[EDIM];
    const float4* ap = (const float4*)(edge_attr + (size_t)e * EDIM);
#pragma unroll
    for (int i = 0; i < EDIM / 4; i++) {
        float4 v = ap[i];
        a[4 * i + 0] = v.x; a[4 * i + 1] = v.y; a[4 * i + 2] = v.z; a[4 * i + 3] = v.w;
    }
    int tt = etype[e];
    float dir  = a[EDIM - 2];
    float pump = a[EDIM - 1];
    float sign = dir * 2.f - 1.f;
    float speed = pump * (dir > 0.f ? dir : 1.f);
    int src = ei[e];
    int dst = ei[EE + e];
    int sp = pos[src];
    int p = atomicAdd(&cur[dst], 1);
#pragma unroll
    for (int l = 0; l < LL; l++) {
        const float* w0 = eWl + ((l * ET + tt) * 2 + 0) * EDIM;
        const float* w1 = w0 + EDIM;
        float r0 = ebd[(l * ET + tt) * 2 + 0];
        float r1 = ebd[(l * ET + tt) * 2 + 1];
#pragma unroll
        for (int c = 0; c < EDIM; c++) { r0 += a[c] * w0[c]; r1 += a[c] * w1[c]; }
        float gain = fmaxf(r0, 0.f) + log1pf(expf(-fabsf(r0)));   // stable softplus
        float bias = 0.f;
        if (tt == 1) { gain *= speed; bias = r1 * speed; }        // PUMP == 1
        esort[(size_t)l * EE + p] = make_float4(__int_as_float(sp), sign * gain, sign * bias, 0.f);
    }
}

// ------------- fused layer: gather + matmul + ReLU + LN + residual -------------
// 32 permuted rows per block; gather: 8 threads/node, each owns a 16-float slice.
__global__ __launch_bounds__(256, 4) void k_layer(const float* __restrict__ h,
                                                  const int* __restrict__ offs,
                                                  const int* __restrict__ deg,
                                                  const int* __restrict__ inv,
                                                  const float4* __restrict__ esortL,
                                                  const float* __restrict__ Wg,
                                                  const float* __restrict__ bg,
                                                  const float* __restrict__ lng,
                                                  const float* __restrict__ lnb,
                                                  const int* __restrict__ meta,
                                                  float* __restrict__ hnext) {
    __shared__ float As[32 * 132];
    __shared__ float Ws[128 * 68];
    int tid = threadIdx.x;
    int m0 = blockIdx.x * 32;
    int tt = (m0 >= meta[3]) ? 1 : 0;
    const float* W = Wg + (size_t)tt * D * D;

    // ---- gather phase ----
    {
        int nl = tid >> 3;                 // node-in-tile 0..31
        int ch = tid & 7;                  // 16-float slice
        int p = m0 + nl;
        int d = inv[p];
        float4 a0 = make_float4(0.f, 0.f, 0.f, 0.f), a1 = a0, a2 = a0, a3 = a0;
        float sA = 0.f, sB = 0.f;
        if (d >= 0) {
            int start = offs[d], n = deg[d];
            const float4* hb = (const float4*)h;
            for (int k = 0; k < n; k++) {
                float4 e = esortL[start + k];
                int sp = __float_as_int(e.x);
                float A = e.y;
                const float4* hr = hb + (size_t)sp * 32 + ch * 4;
                float4 h0 = hr[0], h1 = hr[1], h2 = hr[2], h3 = hr[3];
                a0.x += A * h0.x; a0.y += A * h0.y; a0.z += A * h0.z; a0.w += A * h0.w;
                a1.x += A * h1.x; a1.y += A * h1.y; a1.z += A * h1.z; a1.w += A * h1.w;
                a2.x += A * h2.x; a2.y += A * h2.y; a2.z += A * h2.z; a2.w += A * h2.w;
                a3.x += A * h3.x; a3.y += A * h3.y; a3.z += A * h3.z; a3.w += A * h3.w;
                sA += A; sB += e.z;
            }
            const float4* hd = (const float4*)h + (size_t)p * 32 + ch * 4;
            float4 d0 = hd[0], d1 = hd[1], d2 = hd[2], d3 = hd[3];
            a0.x = a0.x - sA * d0.x + sB; a0.y = a0.y - sA * d0.y + sB;
            a0.z = a0.z - sA * d0.z + sB; a0.w = a0.w - sA * d0.w + sB;
            a1.x = a1.x - sA * d1.x + sB; a1.y = a1.y - sA * d1.y + sB;
            a1.z = a1.z - sA * d1.z + sB; a1.w = a1.w - sA * d1.w + sB;
            a2.x = a2.x - sA * d2.x + sB; a2.y = a2.y - sA * d2.y + sB;
            a2.z = a2.z - sA * d2.z + sB; a2.w = a2.w - sA * d2.w + sB;
            a3.x = a3.x - sA * d3.x + sB; a3.y = a3.y - sA * d3.y + sB;
            a3.z = a3.z - sA * d3.z + sB; a3.w = a3.w - sA * d3.w + sB;
        }
        float* as = &As[nl * 132 + ch * 16];
        *(float4*)(as + 0)  = a0;
        *(float4*)(as + 4)  = a1;
        *(float4*)(as + 8)  = a2;
        *(float4*)(as + 12) = a3;
    }

    int og = tid & 31, mg = tid >> 5;   // o = og+32j, m = mg+8i
    float acc[4][4];
#pragma unroll
    for (int i = 0; i < 4; i++)
#pragma unroll
        for (int j = 0; j < 4; j++) acc[i][j] = 0.f;

    for (int half = 0; half < 2; half++) {
        __syncthreads();
#pragma unroll
        for (int rep = 0; rep < 8; rep++) {
            int flat = rep * 256 + tid;
            int r = flat >> 4, k4 = flat & 15;
            float4 v = *(const float4*)&W[(size_t)r * D + half * 64 + 4 * k4];
            *(float4*)&Ws[r * 68 + 4 * k4] = v;
        }
        __syncthreads();
#pragma unroll
        for (int kk = 0; kk < 64; kk += 4) {
            float4 a[4], wv[4];
#pragma unroll
            for (int i = 0; i < 4; i++) a[i] = *(const float4*)&As[(mg + 8 * i) * 132 + half * 64 + kk];
#pragma unroll
            for (int j = 0; j < 4; j++) wv[j] = *(const float4*)&Ws[(og + 32 * j) * 68 + kk];
#pragma unroll
            for (int i = 0; i < 4; i++)
#pragma unroll
                for (int j = 0; j < 4; j++)
                    acc[i][j] += a[i].x * wv[j].x + a[i].y * wv[j].y + a[i].z * wv[j].z + a[i].w * wv[j].w;
        }
    }

    // epilogue: bias + relu + LN + residual
    float bj[4], gj[4], lj[4];
#pragma unroll
    for (int j = 0; j < 4; j++) {
        int o = og + 32 * j;
        bj[j] = bg[tt * D + o];
        gj[j] = lng[o];
        lj[j] = lnb[o];
    }
    float c[4][4];
#pragma unroll
    for (int i = 0; i < 4; i++)
#pragma unroll
        for (int j = 0; j < 4; j++) c[i][j] = fmaxf(acc[i][j] + bj[j], 0.f);

    float mu[4], rs[4];
#pragma unroll
    for (int i = 0; i < 4; i++) {
        float s = 0.f, s2 = 0.f;
#pragma unroll
        for (int j = 0; j < 4; j++) { s += c[i][j]; s2 += c[i][j] * c[i][j]; }
#pragma unroll
        for (int m = 1; m < 32; m <<= 1) { s += __shfl_xor(s, m); s2 += __shfl_xor(s2, m); }
        float mm = s * (1.f / 128.f);
        float vv = s2 * (1.f / 128.f) - mm * mm;
        mu[i] = mm;
        rs[i] = rsqrtf(vv + 1e-5f);
    }
#pragma unroll
    for (int i = 0; i < 4; i++) {
        int row = m0 + mg + 8 * i;
#pragma unroll
        for (int j = 0; j < 4; j++) {
            int o = og + 32 * j;
            float v = (c[i][j] - mu[i]) * rs[i] * gj[j] + lj[j] + h[(size_t)row * D + o];
            hnext[(size_t)row * D + o] = v;
        }
    }
}

// ------------- final FC, 64-row tiles, un-permuted scatter write -------------
__global__ __launch_bounds__(256, 3) void k_fc(const float* __restrict__ hin,
                                               const float* __restrict__ W,
                                               const float* __restrict__ bias,
                                               const int* __restrict__ inv,
                                               float* __restrict__ out) {
    __shared__ float As[64 * 132];   // 33.8 KB
    __shared__ float Ws[128 * 68];   // 34.8 KB
    int tid = threadIdx.x;
    int m0 = blockIdx.x * 64;
#pragma unroll
    for (int rep = 0; rep < 8; rep++) {
        int flat = rep * 256 + tid;
        int r = flat >> 5, k4 = flat & 31;
        float4 v = *(const float4*)&hin[(size_t)(m0 + r) * D + 4 * k4];
        *(float4*)&As[r * 132 + 4 * k4] = v;
    }
    int og = tid & 31, mg = tid >> 5;   // o = og+32j (j<4), m = mg+8i (i<8)
    float acc[8][4];
#pragma unroll
    for (int i = 0; i < 8; i++)
#pragma unroll
        for (int j = 0; j < 4; j++) acc[i][j] = 0.f;

    for (int half = 0; half < 2; half++) {
        __syncthreads();
#pragma unroll
        for (int rep = 0; rep < 8; rep++) {
            int flat = rep * 256 + tid;
            int r = flat >> 4, k4 = flat & 15;
            float4 v = *(const float4*)&W[(size_t)r * D + half * 64 + 4 * k4];
            *(float4*)&Ws[r * 68 + 4 * k4] = v;
        }
        __syncthreads();
#pragma unroll
        for (int kk = 0; kk < 64; kk += 4) {
            float4 a[8], wv[4];
#pragma unroll
            for (int i = 0; i < 8; i++) a[i] = *(const float4*)&As[(mg + 8 * i) * 132 + half * 64 + kk];
#pragma unroll
            for (int j = 0; j < 4; j++) wv[j] = *(const float4*)&Ws[(og + 32 * j) * 68 + kk];
#pragma unroll
            for (int i = 0; i < 8; i++)
#pragma unroll
                for (int j = 0; j < 4; j++)
                    acc[i][j] += a[i].x * wv[j].x + a[i].y * wv[j].y + a[i].z * wv[j].z + a[i].w * wv[j].w;
        }
    }
    float bj[4];
#pragma unroll
    for (int j = 0; j < 4; j++) bj[j] = bias[og + 32 * j];
#pragma unroll
    for (int i = 0; i < 8; i++) {
        int row = m0 + mg + 8 * i;
        int orig = inv[row];
        if (orig >= 0) {
#pragma unroll
            for (int j = 0; j < 4; j++)
                out[(size_t)orig * D + og + 32 * j] = acc[i][j] + bj[j];
        }
    }
}

extern "C" void kernel_launch(void* const* d_in, const int* in_sizes, int n_in,
                              void* d_out, int out_size, void* d_ws, size_t ws_size,
                              hipStream_t stream) {
    const float* x         = (const float*)d_in[0];
    const float* edge_attr = (const float*)d_in[1];
    const float* node_W    = (const float*)d_in[2];
    const float* node_b    = (const float*)d_in[3];
    const float* edge_W    = (const float*)d_in[4];
    const float* edge_b    = (const float*)d_in[5];
    const float* emb       = (const float*)d_in[6];
    const float* ln_g      = (const float*)d_in[7];
    const float* ln_b      = (const float*)d_in[8];
    const float* fc_W      = (const float*)d_in[9];
    const float* fc_b      = (const float*)d_in[10];
    const int*   edge_index = (const int*)d_in[11];
    const int*   node_type  = (const int*)d_in[12];
    const int*   edge_type  = (const int*)d_in[13];
    float* out = (float*)d_out;

    char* w = (char*)d_ws;
    auto alloc = [&](size_t bytes) {
        void* p = (void*)w;
        w += (bytes + 255) & ~(size_t)255;
        return p;
    };
    float*  P     = (float*)alloc((size_t)NPAD * D * 4);
    float*  Q     = (float*)alloc((size_t)NPAD * D * 4);
    float4* esort = (float4*)alloc((size_t)LL * EE * 16);
    int*    pos   = (int*)alloc((size_t)NN * 4);
    int*    inv   = (int*)alloc((size_t)NPAD * 4);
    int*    deg   = (int*)alloc((size_t)NN * 4);
    int*    offs  = (int*)alloc((size_t)NN * 4);
    int*    cur   = (int*)alloc((size_t)NN * 4);
    int*    bsum  = (int*)alloc(256 * 4);
    int*    boff  = (int*)alloc(256 * 4);
    int*    pc    = (int*)alloc(256 * 4);
    int*    po    = (int*)alloc(256 * 4);
    int*    meta  = (int*)alloc(8 * 4);

    hipMemsetAsync(deg, 0, (size_t)NN * 4, stream);
    hipMemsetAsync(inv, 0xFF, (size_t)NPAD * 4, stream);   // -1 = gap row

    k_pcount<<<NB, 256, 0, stream>>>(node_type, pc);
    k_pscan<<<1, 256, 0, stream>>>(pc, po, meta);
    k_passign<<<NB, 256, 0, stream>>>(node_type, po, meta, pos, inv);
    k_permx<<<(NN * 32 + 255) / 256, 256, 0, stream>>>(x, pos, P);

    k_hist<<<(EE + 255) / 256, 256, 0, stream>>>(edge_index + EE, deg);
    k_scan_bsum<<<NB, 256, 0, stream>>>(deg, bsum);
    k_scan_boff<<<1, 256, 0, stream>>>(bsum, boff);
    k_scan_offs<<<NB, 256, 0, stream>>>(deg, boff, offs, cur);
    k_edge<<<(EE + 255) / 256, 256, 0, stream>>>(edge_attr, edge_W, edge_b, emb,
                                                 edge_index, edge_type, pos, cur, esort);

    const float* hin = P;
    float* outs[LL] = {Q, P, Q};
    for (int l = 0; l < LL; l++) {
        k_layer<<<NT32, 256, 0, stream>>>(hin, offs, deg, inv, esort + (size_t)l * EE,
                                          node_W + (size_t)l * NT * D * D,
                                          node_b + (size_t)l * NT * D,
                                          ln_g + (size_t)l * D,
                                          ln_b + (size_t)l * D,
                                          meta, outs[l]);
        hin = outs[l];
    }
    k_fc<<<NT64, 256, 0, stream>>>(hin, fc_W, fc_b, inv, out);
}